// Round 6
// baseline (158.310 us; speedup 1.0000x reference)
//
#include <hip/hip_runtime.h>
#include <math.h>

// Problem constants
constexpr int B = 2, C = 256, H = 56, W = 96;
constexpr int HW = H * W;

// int8 quantization: scale 127/6 for both fmaps; dots rescaled at the end.
#define SQ 21.166666f                    // 127/6
constexpr float SCL = 36.0f / (127.0f * 127.0f * 16.0f);  // 1/(SQ^2 * sqrt(C))

// Workspace layout (byte offsets, all 16B-aligned)
constexpr size_t F1T_B = 0;                                   // i8 [B,HW,C]
constexpr size_t L0_B  = (size_t)B * HW * C;                  // i8 [B,HW,C]      @ 2,752,512
constexpr size_t L1_B  = L0_B + (size_t)B * HW * C;           // i8 [B,28*48,C]   @ 5,505,024
constexpr size_t L2_B  = L1_B + (size_t)B * 28 * 48 * C;      // i8 [B,14*24,C]
constexpr size_t L3_B  = L2_B + (size_t)B * 14 * 24 * C;      // i8 [B,7*12,C]
constexpr size_t STG_B = L3_B + (size_t)B * 7 * 12 * C;       // fp16 [B,HW,324]  @ 6,408,192
constexpr size_t OUT0_ELEMS = (size_t)B * 324 * HW;

static __device__ __forceinline__ int dot4acc(int a, int b, int c) {
#if __has_builtin(__builtin_amdgcn_sdot4)
    return __builtin_amdgcn_sdot4(a, b, c, false);
#else
    c += (int)(char)(a) * (int)(char)(b);
    c += (int)(char)(a >> 8) * (int)(char)(b >> 8);
    c += (int)(char)(a >> 16) * (int)(char)(b >> 16);
    c += (int)(char)(a >> 24) * (int)(char)(b >> 24);
    return c;
#endif
}

static __device__ __forceinline__ unsigned short pack_i8x2(float a, float b) {
    int ia = (int)rintf(a); ia = ia < -127 ? -127 : (ia > 127 ? 127 : ia);
    int ib = (int)rintf(b); ib = ib < -127 ? -127 : (ib > 127 ? 127 : ib);
    return (unsigned short)((ia & 0xFF) | ((ib & 0xFF) << 8));
}

// [B,C,HW] fp32 -> channel-last int8 (scale SQ) for both fmap1 and fmap2.
// grid (HW/32, C/64, 2*B), block (32,8). Tile: 64 ch x 32 q.
__global__ void transpose_in(const float* __restrict__ fmap1,
                             const float* __restrict__ fmap2,
                             char* __restrict__ ws) {
    __shared__ float tile[64][33];
    int z = blockIdx.z;
    int b = z & 1, m = z >> 1;                 // m=0: fmap1, m=1: fmap2
    const float* src = m ? fmap2 : fmap1;
    unsigned short* dst = (unsigned short*)(ws + (m ? L0_B : F1T_B));
    int c0 = blockIdx.y * 64, q0 = blockIdx.x * 32;
    int tx = threadIdx.x, ty = threadIdx.y;
#pragma unroll
    for (int r = 0; r < 8; ++r) {
        int cl = ty + r * 8;
        tile[cl][tx] = src[((size_t)(b * C + c0 + cl)) * HW + q0 + tx];
    }
    __syncthreads();
#pragma unroll
    for (int r = 0; r < 4; ++r) {
        int pl = ty + r * 8;
        dst[((size_t)b * HW + q0 + pl) * 128 + (c0 >> 1) + tx] =
            pack_i8x2(tile[2 * tx][pl] * SQ, tile[2 * tx + 1][pl] * SQ);
    }
}

// Build pyramid levels 1..3 directly from i8 L0; one thread per channel PAIR.
constexpr int NP1 = B * 28 * 48 * C / 2;   // 344,064
constexpr int NP2 = B * 14 * 24 * C / 2;   //  86,016
constexpr int NP3 = B * 7 * 12 * C / 2;    //  21,504
__global__ void build_pools(char* __restrict__ ws) {
    const unsigned short* L0p = (const unsigned short*)(ws + L0_B);
    int t = blockIdx.x * 256 + threadIdx.x;
    int l, tl;
    if (t < NP1)             { l = 1; tl = t; }
    else if (t < NP1 + NP2)  { l = 2; tl = t - NP1; }
    else                     { l = 3; tl = t - NP1 - NP2; }
    int Wo = W >> l, Ho = H >> l, S = 1 << l;
    int c2 = tl & 127;
    int r = tl >> 7;
    int x = r % Wo; r /= Wo;
    int y = r % Ho;
    int b = r / Ho;
    int sx = 0, sy = 0;
    for (int dy = 0; dy < S; ++dy)
        for (int dx = 0; dx < S; ++dx) {
            unsigned short v = L0p[((size_t)(b * H + y * S + dy) * W + x * S + dx) * 128 + c2];
            sx += (int)(char)(v & 0xFF);
            sy += (int)(char)(v >> 8);
        }
    float inv = 1.0f / (S * S);
    unsigned short* dst = (unsigned short*)(ws + (l == 1 ? L1_B : (l == 2 ? L2_B : L3_B)));
    dst[tl] = pack_i8x2((float)sx * inv, (float)sy * inv);
}

// One block per query pixel; wave l = pyramid level l.
// 8 groups x 8 lanes; each group handles a COLUMN PAIR (positions 2g,2g+1 —
// always in the same row, since row width 10 is even): one y-check + one row
// base per pair. 7 iters x 16 positions cover 100. Fold trick merges the two
// accumulators into one 3-shfl reduce.
__global__ __launch_bounds__(256) void corr_lookup(
    const float* __restrict__ coords, const char* __restrict__ ws,
    _Float16* __restrict__ stage) {
    int q = blockIdx.x;
    int w = q % W;
    int t2 = q / W;
    int h = t2 % H;
    int b = t2 / H;
    int tid = threadIdx.x;

    __shared__ float Dsh[4][100];

    int wave = tid >> 6, lane = tid & 63, u = lane & 7, grp = lane >> 3;

    // f1 fragment: 32 contiguous channels per lane (32 B = 2x int4)
    const int4* ap = (const int4*)(ws + F1T_B + ((size_t)b * HW + h * W + w) * C);
    int4 A0 = ap[2 * u], A1 = ap[2 * u + 1];

    int l = wave;
    int Hl = H >> l, Wl = W >> l;
    size_t off = (l == 0 ? L0_B : (l == 1 ? L1_B : (l == 2 ? L2_B : L3_B)));
    const char* base8 = ws + off + (size_t)b * Hl * Wl * C;

    float cx = coords[((size_t)(b * 2 + 0)) * HW + h * W + w];
    float cy = coords[((size_t)(b * 2 + 1)) * HW + h * W + w];
    float scale = 1.0f / (float)(1 << l);
    float fx = cx * scale, fy = cy * scale;
    float fxf = floorf(fx), fyf = floorf(fy);
    float wx = fx - fxf, wy = fy - fyf;
    int ix = (int)fxf, iy = (int)fyf;

    // p0 = it*16 + 2*grp; yy = p0/10, xx = p0%10 (xx always even)
    int ix4 = ix - 4;
    int xx = (2 * grp < 10) ? 2 * grp : 2 * grp - 10;
    int y  = iy - 4 + (2 * grp >= 10 ? 1 : 0);
    int x  = ix4 + xx;
    int p0 = 2 * grp;

#pragma unroll
    for (int it = 0; it < 7; ++it) {
        bool live = (it < 6) | (grp < 2);      // p0 < 100
        int s0 = 0, s1 = 0;
        bool yok = live & ((unsigned)y < (unsigned)Hl);
        const char* row = base8 + (size_t)(y * Wl) * 256 + u * 32;
        if (yok & ((unsigned)x < (unsigned)Wl)) {
            const int4* cp = (const int4*)(row + x * 256);
            int4 c0 = cp[0], c1 = cp[1];
            s0 = dot4acc(c0.x, A0.x, s0);
            s0 = dot4acc(c0.y, A0.y, s0);
            s0 = dot4acc(c0.z, A0.z, s0);
            s0 = dot4acc(c0.w, A0.w, s0);
            s0 = dot4acc(c1.x, A1.x, s0);
            s0 = dot4acc(c1.y, A1.y, s0);
            s0 = dot4acc(c1.z, A1.z, s0);
            s0 = dot4acc(c1.w, A1.w, s0);
        }
        if (yok & ((unsigned)(x + 1) < (unsigned)Wl)) {
            const int4* cp = (const int4*)(row + (x + 1) * 256);
            int4 c0 = cp[0], c1 = cp[1];
            s1 = dot4acc(c0.x, A0.x, s1);
            s1 = dot4acc(c0.y, A0.y, s1);
            s1 = dot4acc(c0.z, A0.z, s1);
            s1 = dot4acc(c0.w, A0.w, s1);
            s1 = dot4acc(c1.x, A1.x, s1);
            s1 = dot4acc(c1.y, A1.y, s1);
            s1 = dot4acc(c1.z, A1.z, s1);
            s1 = dot4acc(c1.w, A1.w, s1);
        }
        // fold: lanes u<4 reduce s0, lanes u>=4 reduce s1 (one xor4 + 2 shfl)
        int v = ((u & 4) ? s1 : s0) + __shfl_xor((u & 4) ? s0 : s1, 4);
        v += __shfl_xor(v, 1);
        v += __shfl_xor(v, 2);
        if (live && (u & 3) == 0) Dsh[wave][p0 + (u >> 2)] = (float)v * SCL;
        // advance p0 by 16
        xx += 6;
        int c = (xx >= 10);
        xx -= c ? 10 : 0;
        y += c ? 2 : 1;
        x = ix4 + xx;
        p0 += 16;
    }
    __syncthreads();

    // 81 bilinear combines; o: x-offset = o/9 (slow), y-offset = o%9 (fast)
    size_t bse = ((size_t)b * HW + h * W + w) * 324 + l * 81;
    for (int o = lane; o < 81; o += 64) {
        int xo = o / 9;
        int yo = o - xo * 9;
        float v00 = Dsh[wave][yo * 10 + xo];
        float v01 = Dsh[wave][yo * 10 + xo + 1];
        float v10 = Dsh[wave][(yo + 1) * 10 + xo];
        float v11 = Dsh[wave][(yo + 1) * 10 + xo + 1];
        float s = (1.f - wy) * ((1.f - wx) * v00 + wx * v01)
                +        wy  * ((1.f - wx) * v10 + wx * v11);
        stage[bse + o] = (_Float16)s;
    }
}

// Fused tail: blocks [0,3696) transpose stage->out0; blocks [3696,4592) convex upsample.
constexpr int T_BLOCKS = 168 * 11 * B;   // 3696
__global__ __launch_bounds__(256) void tail_kernel(
    const _Float16* __restrict__ stage, const float* __restrict__ flow,
    const float* __restrict__ mask, float* __restrict__ out0,
    float* __restrict__ out1) {
    __shared__ float smem[72 * 96 + 2 * 3 * 98];
    int blk = blockIdx.x;
    int tid = threadIdx.x;

    if (blk < T_BLOCKS) {
        float (*tile)[33] = (float(*)[33])smem;
        int b = blk / (168 * 11);
        int rem = blk % (168 * 11);
        int by = rem / 168, bx = rem % 168;
        int ch0 = by * 32, q0 = bx * 32;
        int tx = tid & 31, ty = tid >> 5;
#pragma unroll
        for (int r = 0; r < 4; ++r) {
            int pl = ty + r * 8;
            if (ch0 + tx < 324)
                tile[pl][tx] = (float)stage[((size_t)b * HW + q0 + pl) * 324 + ch0 + tx];
        }
        __syncthreads();
#pragma unroll
        for (int r = 0; r < 4; ++r) {
            int chl = ty + r * 8;
            if (ch0 + chl < 324)
                out0[((size_t)(b * 324 + ch0 + chl)) * HW + q0 + tx] = tile[tx][chl];
        }
        return;
    }

    float* msk = smem;               // 72*96
    float* fst = smem + 72 * 96;     // 2*3*98
    int cb = blk - T_BLOCKS;
    int i = cb & 7;
    int r = cb >> 3;
    int h = r % H;
    int b = r / H;

    for (int idx = tid; idx < 72 * 96; idx += 256) {
        int row = idx / 96, wc = idx - row * 96;
        int k = row >> 3, j = row & 7;
        int gl = k * 64 + i * 8 + j;
        msk[idx] = mask[((size_t)(b * 576 + gl)) * HW + h * W + wc];
    }
    for (int idx = tid; idx < 588; idx += 256) {
        int ch = idx / 294;
        int rem2 = idx - ch * 294;
        int rr = rem2 / 98;
        int xw = rem2 - rr * 98;
        int hh = h + rr - 1, ww = xw - 1;
        float v = 0.f;
        if (hh >= 0 && hh < H && ww >= 0 && ww < W)
            v = 8.0f * flow[((size_t)(b * 2 + ch)) * HW + hh * W + ww];
        fst[idx] = v;
    }
    __syncthreads();

#pragma unroll
    for (int rr = 0; rr < 3; ++rr) {
        int col = tid + rr * 256;    // 0..767
        int w = col >> 3, j = col & 7;
        float m[9], mx = -1e30f;
#pragma unroll
        for (int k = 0; k < 9; ++k) {
            m[k] = msk[(k * 8 + j) * 96 + w];
            mx = fmaxf(mx, m[k]);
        }
        float sum = 0.f;
#pragma unroll
        for (int k = 0; k < 9; ++k) {
            m[k] = __expf(m[k] - mx);
            sum += m[k];
        }
        float inv = 1.0f / sum;
        float a0 = 0.f, a1 = 0.f;
#pragma unroll
        for (int k = 0; k < 9; ++k) {
            int ki = k / 3, kj = k - ki * 3;
            float wgt = m[k] * inv;
            a0 = fmaf(wgt, fst[0 * 294 + ki * 98 + w + kj], a0);
            a1 = fmaf(wgt, fst[1 * 294 + ki * 98 + w + kj], a1);
        }
        size_t row8 = (size_t)8 * h + i;
        out1[((size_t)(b * 2 + 0) * 448 + row8) * 768 + col] = a0;
        out1[((size_t)(b * 2 + 1) * 448 + row8) * 768 + col] = a1;
    }
}

extern "C" void kernel_launch(void* const* d_in, const int* in_sizes, int n_in,
                              void* d_out, int out_size, void* d_ws, size_t ws_size,
                              hipStream_t stream) {
    const float* fmap1  = (const float*)d_in[0];
    const float* fmap2  = (const float*)d_in[1];
    const float* coords = (const float*)d_in[2];
    const float* flow   = (const float*)d_in[3];
    const float* maskp  = (const float*)d_in[4];
    float* out = (float*)d_out;
    char* ws = (char*)d_ws;
    _Float16* stage = (_Float16*)(ws + STG_B);

    transpose_in<<<dim3(HW / 32, C / 64, 2 * B), dim3(32, 8), 0, stream>>>(fmap1, fmap2, ws);
    build_pools<<<(NP1 + NP2 + NP3) / 256, 256, 0, stream>>>(ws);
    corr_lookup<<<B * HW, 256, 0, stream>>>(coords, ws, stage);
    tail_kernel<<<T_BLOCKS + B * H * 8, 256, 0, stream>>>(stage, flow, maskp, out, out + OUT0_ELEMS);
}